// Round 10
// baseline (1147.439 us; speedup 1.0000x reference)
//
#include <hip/hip_runtime.h>

#define S 1024
#define MDIM 1024
#define NH 16
#define HD 64
#define NKV 8
#define FF 3072
#define NE 64
#define TOPK 8
#define CAP 256

typedef unsigned short u16;
typedef __attribute__((ext_vector_type(8))) short bf16x8;
typedef __attribute__((ext_vector_type(4))) float f32x4;

__device__ __forceinline__ u16 f2bf(float f) {
    union { float f; unsigned u; } x; x.f = f;
    unsigned r = x.u + 0x7FFFu + ((x.u >> 16) & 1u);
    return (u16)(r >> 16);
}
__device__ __forceinline__ float bf2f(u16 b) {
    union { unsigned u; float f; } x; x.u = ((unsigned)b) << 16;
    return x.f;
}
__device__ __forceinline__ void split1(float x, u16& h, u16& l) {
    h = f2bf(x);
    l = f2bf(x - bf2f(h));
}
// swizzled column (u16 units) for k-octet G in row `row` of a [R][40] B-tile
__device__ __forceinline__ int swzcol(int row, int G) { return 8 * (G ^ ((row >> 3) & 3)); }

// 16B global->LDS DMA (dest = wave-uniform base + lane*16)
__device__ __forceinline__ void gl_lds16(const u16* g, u16* l) {
    __builtin_amdgcn_global_load_lds(
        (const __attribute__((address_space(1))) unsigned int*)g,
        (__attribute__((address_space(3))) unsigned int*)l, 16, 0, 0);
}

// ---------------- RMS norm 1: writes pre-split bf16 hi/lo ----------------
__global__ __launch_bounds__(256) void k_rms1(const float* __restrict__ x,
                                              const float* __restrict__ w,
                                              u16* __restrict__ ohi,
                                              u16* __restrict__ olo) {
    int s = blockIdx.x;
    const float* row = x + (size_t)s * MDIM;
    float v[4]; float ss = 0.f;
#pragma unroll
    for (int i = 0; i < 4; ++i) { v[i] = row[threadIdx.x + i * 256]; ss += v[i] * v[i]; }
#pragma unroll
    for (int of = 32; of; of >>= 1) ss += __shfl_xor(ss, of);
    __shared__ float red[4];
    int wid = threadIdx.x >> 6;
    if ((threadIdx.x & 63) == 0) red[wid] = ss;
    __syncthreads();
    float tot = red[0] + red[1] + red[2] + red[3];
    float sc = rsqrtf(tot * (1.f / MDIM) + 1e-6f);
#pragma unroll
    for (int i = 0; i < 4; ++i) {
        int c = threadIdx.x + i * 256;
        float ov = v[i] * sc * w[c];
        u16 hh, ll; split1(ov, hh, ll);
        ohi[(size_t)s * MDIM + c] = hh;
        olo[(size_t)s * MDIM + c] = ll;
    }
}

// ---------------- 3-term split GEMM, pipelined + gload_lds A ----------------
// EPI: 0 = f32 out, 1 = f32 out + resid
template <int EPI>
__global__ __launch_bounds__(256) void k_gemm_split(
    const u16* __restrict__ Ahi, const u16* __restrict__ Alo, int lda,
    const float* __restrict__ B, int ldb,
    float* __restrict__ C, int ldc,
    const float* __restrict__ resid, int M, int K) {
    int m0 = blockIdx.y * 64;
    int n0 = blockIdx.x * 64;
    __shared__ u16 Ah[2][64][32];
    __shared__ u16 Al[2][64][32];
    __shared__ u16 Bh[2][64][40];
    __shared__ u16 Bl[2][64][40];
    int tid = threadIdx.x, lane = tid & 63, wid = tid >> 6;
    int wm = (wid >> 1) * 32, wn = (wid & 1) * 32;
    f32x4 acc[2][2] = {};

    int rt = wid * 16 + (lane >> 2);
    int gsrc = (lane & 3) ^ ((lane >> 4) & 3);
    const u16* ahb = Ahi + (size_t)(m0 + rt) * lda + gsrc * 8;
    const u16* alb = Alo + (size_t)(m0 + rt) * lda + gsrc * 8;

    int nB = tid & 63, kbB = tid >> 6;
    int colB = swzcol(nB, kbB);
    float rb[8];
    auto loadB = [&](int k0) {
        const float* bp = B + (size_t)(k0 + kbB * 8) * ldb + n0 + nB;
#pragma unroll
        for (int i = 0; i < 8; ++i) rb[i] = bp[(size_t)i * ldb];
    };
    auto stageA = [&](int b, int k0) {
        gl_lds16(ahb + k0, &Ah[b][wid * 16][0]);
        gl_lds16(alb + k0, &Al[b][wid * 16][0]);
    };
    auto writeB = [&](int b) {
        bf16x8 hh, ll;
#pragma unroll
        for (int i = 0; i < 8; ++i) { u16 h, l; split1(rb[i], h, l); hh[i] = (short)h; ll[i] = (short)l; }
        *(bf16x8*)&Bh[b][nB][colB] = hh;
        *(bf16x8*)&Bl[b][nB][colB] = ll;
    };

    loadB(0); stageA(0, 0); writeB(0);
    __syncthreads();
    int NT = K / 32;
    for (int t = 0; t < NT; ++t) {
        int c = t & 1;
        if (t + 1 < NT) { loadB((t + 1) * 32); stageA(1 - c, (t + 1) * 32); }
        bf16x8 ah[2], al[2], bh[2], bl[2];
#pragma unroll
        for (int mi = 0; mi < 2; ++mi) {
            int r = wm + mi * 16 + (lane & 15);
            int cA = 8 * ((lane >> 4) ^ ((r >> 2) & 3));
            ah[mi] = *(const bf16x8*)&Ah[c][r][cA];
            al[mi] = *(const bf16x8*)&Al[c][r][cA];
        }
#pragma unroll
        for (int ni = 0; ni < 2; ++ni) {
            int r = wn + ni * 16 + (lane & 15);
            int cc = swzcol(r, lane >> 4);
            bh[ni] = *(const bf16x8*)&Bh[c][r][cc];
            bl[ni] = *(const bf16x8*)&Bl[c][r][cc];
        }
#pragma unroll
        for (int mi = 0; mi < 2; ++mi)
#pragma unroll
            for (int ni = 0; ni < 2; ++ni) {
                acc[mi][ni] = __builtin_amdgcn_mfma_f32_16x16x32_bf16(ah[mi], bh[ni], acc[mi][ni], 0, 0, 0);
                acc[mi][ni] = __builtin_amdgcn_mfma_f32_16x16x32_bf16(ah[mi], bl[ni], acc[mi][ni], 0, 0, 0);
                acc[mi][ni] = __builtin_amdgcn_mfma_f32_16x16x32_bf16(al[mi], bh[ni], acc[mi][ni], 0, 0, 0);
            }
        if (t + 1 < NT) { writeB(1 - c); __syncthreads(); }
    }
#pragma unroll
    for (int mi = 0; mi < 2; ++mi)
#pragma unroll
        for (int ni = 0; ni < 2; ++ni)
#pragma unroll
            for (int r = 0; r < 4; ++r) {
                int row = m0 + wm + mi * 16 + (lane >> 4) * 4 + r;
                int col = n0 + wn + ni * 16 + (lane & 15);
                float v = acc[mi][ni][r];
                if constexpr (EPI == 1) v += resid[(size_t)row * ldc + col];
                C[(size_t)row * ldc + col] = v;
            }
}

// ---------------- 1-term bf16 GEMM, 2-phase pipelined (round-7 form), 3D grid ----------------
template <int TM, int TN, bool SWIGLU>
__global__ __launch_bounds__(256) void k_gemm_bf(
    const u16* __restrict__ A, int lda, long sAe,
    const float* __restrict__ B, long sBe, int ldb,
    u16* __restrict__ C, int ldc, long sCe,
    int K, int pairOff,
    const int* __restrict__ counts, const int* __restrict__ rowidx,
    const u16* __restrict__ Ash, const float* __restrict__ Bsh,
    u16* __restrict__ Csh, int Msh) {
    int z = blockIdx.z, byy = blockIdx.y, bxx = blockIdx.x;
    int tid = threadIdx.x, lane = tid & 63, wid = tid >> 6;
    int M, m0;
    const int* ridx = nullptr;
    if (z >= NE) {
        int mslot = (z - NE) * 2 + byy;
        m0 = mslot * TM;
        M = Msh;
        A = Ash; B = Bsh; C = Csh;
        if (m0 >= M) return;
    } else {
        M = counts[z];
        m0 = byy * TM;
        if (m0 >= M) return;
        A += (size_t)z * sAe;
        B += (size_t)z * sBe;
        C += (size_t)z * sCe;
        if (rowidx) ridx = rowidx + z * CAP;
    }
    int n0 = bxx * TN;

    __shared__ u16 As[2][TM][32];
    __shared__ u16 Bs[2][TN][40];
    __shared__ u16 B2s[2][SWIGLU ? TN : 1][40];

    constexpr int MF = TM / 32;
    constexpr int NI = TN / 32;
    int wm = (wid >> 1) * (TM / 2), wn = (wid & 1) * (TN / 2);

    f32x4 acc[MF][NI] = {};
    f32x4 acc2[SWIGLU ? MF : 1][NI] = {};

    constexpr int NCH = TM / 16;
    constexpr int CPW = (NCH + 3) / 4;
    int arow_in = lane >> 2;
    int gsrc = (lane & 3) ^ ((lane >> 4) & 3);
    const u16* abase[CPW];
#pragma unroll
    for (int i = 0; i < CPW; ++i) {
        int ch = wid + i * 4;
        const u16* p = A;
        if (ch < NCH) {
            int rti = ch * 16 + arow_in;
            int gm = m0 + rti;
            long grow = (gm < M) ? (ridx ? (long)ridx[gm] : (long)gm) : 0;
            p = A + grow * (size_t)lda + gsrc * 8;
        }
        abase[i] = p;
    }
    auto stageA = [&](int b, int k0) {
#pragma unroll
        for (int i = 0; i < CPW; ++i) {
            int ch = wid + i * 4;
            if (ch < NCH) gl_lds16(abase[i] + k0, &As[b][ch * 16][0]);
        }
    };

    constexpr int NKG = 256 / TN;
    constexpr int OPT = 4 / NKG;
    int nB = tid % TN, kgB = tid / TN;
    float rb[OPT][8], rg[SWIGLU ? OPT : 1][8];
    auto loadB = [&](int k0) {
        const float* bp = B + (size_t)(k0 + kgB * OPT * 8) * ldb + n0 + nB;
#pragma unroll
        for (int j = 0; j < OPT; ++j)
#pragma unroll
            for (int i = 0; i < 8; ++i) {
                rb[j][i] = bp[(size_t)(j * 8 + i) * ldb];
                if constexpr (SWIGLU) rg[j][i] = bp[(size_t)(j * 8 + i) * ldb + pairOff];
            }
    };
    auto writeB = [&](int b) {
#pragma unroll
        for (int j = 0; j < OPT; ++j) {
            int col = swzcol(nB, kgB * OPT + j);
            bf16x8 v;
#pragma unroll
            for (int i = 0; i < 8; ++i) v[i] = (short)f2bf(rb[j][i]);
            *(bf16x8*)&Bs[b][nB][col] = v;
            if constexpr (SWIGLU) {
                bf16x8 g;
#pragma unroll
                for (int i = 0; i < 8; ++i) g[i] = (short)f2bf(rg[j][i]);
                *(bf16x8*)&B2s[b][nB][col] = g;
            }
        }
    };

    loadB(0); stageA(0, 0); writeB(0);
    __syncthreads();
    int NT = K / 32;
    for (int t = 0; t < NT; ++t) {
        int c = t & 1;
        if (t + 1 < NT) { loadB((t + 1) * 32); stageA(1 - c, (t + 1) * 32); }
        bf16x8 af[MF], bfr[NI], gfr[SWIGLU ? NI : 1];
#pragma unroll
        for (int mi = 0; mi < MF; ++mi) {
            int r = wm + mi * 16 + (lane & 15);
            int cA = 8 * ((lane >> 4) ^ ((r >> 2) & 3));
            af[mi] = *(const bf16x8*)&As[c][r][cA];
        }
#pragma unroll
        for (int ni = 0; ni < NI; ++ni) {
            int r = wn + ni * 16 + (lane & 15);
            int cB = swzcol(r, lane >> 4);
            bfr[ni] = *(const bf16x8*)&Bs[c][r][cB];
            if constexpr (SWIGLU) gfr[ni] = *(const bf16x8*)&B2s[c][r][cB];
        }
#pragma unroll
        for (int mi = 0; mi < MF; ++mi)
#pragma unroll
            for (int ni = 0; ni < NI; ++ni) {
                acc[mi][ni] = __builtin_amdgcn_mfma_f32_16x16x32_bf16(af[mi], bfr[ni], acc[mi][ni], 0, 0, 0);
                if constexpr (SWIGLU)
                    acc2[mi][ni] = __builtin_amdgcn_mfma_f32_16x16x32_bf16(af[mi], gfr[ni], acc2[mi][ni], 0, 0, 0);
            }
        if (t + 1 < NT) { writeB(1 - c); __syncthreads(); }
    }
#pragma unroll
    for (int mi = 0; mi < MF; ++mi)
#pragma unroll
        for (int ni = 0; ni < NI; ++ni)
#pragma unroll
            for (int r = 0; r < 4; ++r) {
                int row = m0 + wm + mi * 16 + (lane >> 4) * 4 + r;
                int col = n0 + wn + ni * 16 + (lane & 15);
                if (row >= M) continue;
                float x1 = acc[mi][ni][r];
                if constexpr (SWIGLU) {
                    float x2 = acc2[mi][ni][r];
                    x1 = x1 * (x2 / (1.f + __expf(-x2)));
                }
                C[(size_t)row * ldc + col] = f2bf(x1);
            }
}

// ---------------- register-streaming GEMM (no LDS, no barriers): expert/shared down ----------------
// Each wave owns all TM rows x TN/4 cols; B frags loaded directly global->reg (converted once),
// A frags 16B contiguous. Accumulation order identical to the LDS version -> bit-identical output.
template <int TM, int TN>
__global__ __launch_bounds__(256) void k_gemm_reg(
    const u16* __restrict__ A, int lda, long sAe,
    const float* __restrict__ B, long sBe, int ldb,
    u16* __restrict__ C, int ldc, long sCe,
    int K,
    const int* __restrict__ counts,
    const u16* __restrict__ Ash, const float* __restrict__ Bsh,
    u16* __restrict__ Csh, int Msh) {
    // XCD-affinity 1D decode (1088 blocks): same-z blocks share id%8 -> same XCD (A-panel L2 reuse)
    int id = blockIdx.x;
    int z, byy, bxx;
    if (id < 1024) { byy = id >> 9; int t = id & 511; z = ((t >> 6) << 3) | (t & 7); bxx = (t >> 3) & 7; }
    else { int ms = id - 1024; z = NE + (ms >> 4); byy = (ms >> 3) & 1; bxx = ms & 7; }
    int tid = threadIdx.x, lane = tid & 63, w = tid >> 6;
    int M, m0;
    if (z >= NE) {
        int mslot = (z - NE) * 2 + byy;
        m0 = mslot * TM;
        M = Msh;
        A = Ash; B = Bsh; C = Csh;
        if (m0 >= M) return;
    } else {
        M = counts[z];
        m0 = byy * TM;
        if (m0 >= M) return;
        A += (size_t)z * sAe;
        B += (size_t)z * sBe;
        C += (size_t)z * sCe;
    }
    int n0 = bxx * TN;
    constexpr int MF = TM / 16;          // 10 row-frags (wave covers all TM rows)
    constexpr int NI = TN / 64;          // 2 col-frags (TN/4 cols per wave)
    int rgrp = lane >> 4, l16 = lane & 15;
    int wn = n0 + w * (TN / 4);

    f32x4 acc[MF][NI] = {};
    const u16* ab[MF];
#pragma unroll
    for (int mi = 0; mi < MF; ++mi)
        ab[mi] = A + (size_t)(m0 + mi * 16 + l16) * lda + rgrp * 8;
    const float* bb[NI];
#pragma unroll
    for (int ni = 0; ni < NI; ++ni)
        bb[ni] = B + (size_t)(rgrp * 8) * ldb + wn + ni * 16 + l16;

    int NT = K / 32;
    for (int t = 0; t < NT; ++t) {
        bf16x8 bf[NI];
#pragma unroll
        for (int ni = 0; ni < NI; ++ni) {
            const float* bp = bb[ni] + (size_t)t * 32 * ldb;
            bf16x8 v;
#pragma unroll
            for (int i = 0; i < 8; ++i) v[i] = (short)f2bf(bp[(size_t)i * ldb]);
            bf[ni] = v;
        }
        bf16x8 af[MF];
#pragma unroll
        for (int mi = 0; mi < MF; ++mi) af[mi] = *(const bf16x8*)(ab[mi] + t * 32);
#pragma unroll
        for (int mi = 0; mi < MF; ++mi)
#pragma unroll
            for (int ni = 0; ni < NI; ++ni)
                acc[mi][ni] = __builtin_amdgcn_mfma_f32_16x16x32_bf16(af[mi], bf[ni], acc[mi][ni], 0, 0, 0);
    }
#pragma unroll
    for (int mi = 0; mi < MF; ++mi)
#pragma unroll
        for (int ni = 0; ni < NI; ++ni)
#pragma unroll
            for (int r = 0; r < 4; ++r) {
                int row = m0 + mi * 16 + rgrp * 4 + r;
                if (row >= M) continue;
                int col = wn + ni * 16 + l16;
                C[(size_t)row * ldc + col] = f2bf(acc[mi][ni][r]);
            }
}

// ---------------- unpack QKV + RoPE + q/k RMS norm -> pre-split bf16 hi/lo ----------------
__global__ __launch_bounds__(256) void k_rope(const float* __restrict__ qkv,
                                              const float* __restrict__ cosb,
                                              const float* __restrict__ sinb,
                                              const float* __restrict__ qn_w,
                                              const float* __restrict__ kn_w,
                                              u16* __restrict__ qh, u16* __restrict__ ql,
                                              u16* __restrict__ kh, u16* __restrict__ kl,
                                              u16* __restrict__ vh, u16* __restrict__ vl) {
    int wid = threadIdx.x >> 6, lane = threadIdx.x & 63;
    int idx = blockIdx.x * 4 + wid;   // 0..8191
    int s = idx >> 3, j = idx & 7;
    const float* base = qkv + (size_t)s * 2048 + j * 256;
    float c = cosb[s * HD + lane], sn = sinb[s * HD + lane];
    u16 hh, ll;
    split1(base[192 + lane], hh, ll);
    vh[((size_t)j * S + s) * HD + lane] = hh;
    vl[((size_t)j * S + s) * HD + lane] = ll;
#pragma unroll
    for (int r = 0; r < 3; ++r) {
        float x = base[r * 64 + lane];
        float xp = __shfl_xor(x, 32);
        float rot = (lane < 32) ? -xp : xp;
        float y = x * c + rot * sn;
        float ss = y * y;
#pragma unroll
        for (int o = 32; o; o >>= 1) ss += __shfl_xor(ss, o);
        float scale = rsqrtf(ss * (1.f / 64.f) + 1e-6f);
        float outv = y * scale * ((r == 2) ? kn_w[lane] : qn_w[lane]);
        split1(outv, hh, ll);
        if (r == 2) {
            kh[((size_t)j * S + s) * HD + lane] = hh;
            kl[((size_t)j * S + s) * HD + lane] = ll;
        } else {
            qh[((size_t)(j * 2 + r) * S + s) * HD + lane] = hh;
            ql[((size_t)(j * 2 + r) * S + s) * HD + lane] = ll;
        }
    }
}

// ---------------- fused flash attention: per (h, 64-q tile), online softmax ----------------
__global__ __launch_bounds__(256) void k_attn(const u16* __restrict__ qh, const u16* __restrict__ ql,
                                              const u16* __restrict__ kmh, const u16* __restrict__ kml,
                                              const u16* __restrict__ vmh, const u16* __restrict__ vml,
                                              u16* __restrict__ aoh, u16* __restrict__ aol) {
    int qt = 15 - blockIdx.x;       // big tiles first
    int h = blockIdx.y;
    int q0 = qt * 64;
    size_t qoff = (size_t)h * S * HD;
    size_t koff = (size_t)(h >> 1) * S * HD;
    size_t voff = koff;

    __shared__ u16 Vh[64][72];
    __shared__ u16 Vl[64][72];
    __shared__ u16 Ph_l[4][16][72];
    __shared__ u16 Pl_l[4][16][72];

    int tid = threadIdx.x, lane = tid & 63, w = tid >> 6;
    int rgrp = lane >> 4;           // 0..3
    int l16 = lane & 15;

    bf16x8 qfh[2], qfl[2];
#pragma unroll
    for (int ks = 0; ks < 2; ++ks) {
        size_t o = qoff + (size_t)(q0 + w * 16 + l16) * HD + ks * 32 + rgrp * 8;
        qfh[ks] = *(const bf16x8*)(qh + o);
        qfl[ks] = *(const bf16x8*)(ql + o);
    }

    float m_[4], l_[4];
    f32x4 o_[4] = {};
#pragma unroll
    for (int r = 0; r < 4; ++r) { m_[r] = -1e30f; l_[r] = 0.f; }

    for (int kt = 0; kt <= qt; ++kt) {
        int kc = kt * 64;
#pragma unroll
        for (int i = 0; i < 16; ++i) {
            int idx = tid + i * 256;
            int kr = idx >> 6, d = idx & 63;
            Vh[d][kr] = vmh[voff + (size_t)(kc + kr) * HD + d];
            Vl[d][kr] = vml[voff + (size_t)(kc + kr) * HD + d];
        }
        __syncthreads();

        f32x4 sacc[4] = {};
#pragma unroll
        for (int ks = 0; ks < 2; ++ks) {
            bf16x8 bh[4], bl[4];
#pragma unroll
            for (int ni = 0; ni < 4; ++ni) {
                size_t o = koff + (size_t)(kc + ni * 16 + l16) * HD + ks * 32 + rgrp * 8;
                bh[ni] = *(const bf16x8*)(kmh + o);
                bl[ni] = *(const bf16x8*)(kml + o);
            }
#pragma unroll
            for (int ni = 0; ni < 4; ++ni) {
                sacc[ni] = __builtin_amdgcn_mfma_f32_16x16x32_bf16(qfh[ks], bh[ni], sacc[ni], 0, 0, 0);
                sacc[ni] = __builtin_amdgcn_mfma_f32_16x16x32_bf16(qfh[ks], bl[ni], sacc[ni], 0, 0, 0);
                sacc[ni] = __builtin_amdgcn_mfma_f32_16x16x32_bf16(qfl[ks], bh[ni], sacc[ni], 0, 0, 0);
            }
        }
#pragma unroll
        for (int ni = 0; ni < 4; ++ni)
#pragma unroll
            for (int r = 0; r < 4; ++r) {
                int qrow = q0 + w * 16 + rgrp * 4 + r;
                int col = kc + ni * 16 + l16;
                float sv = sacc[ni][r] * 0.125f;
                sacc[ni][r] = (col > qrow) ? -1e30f : sv;
            }
        float pm[4], mnew[4], sf[4], ps[4];
#pragma unroll
        for (int r = 0; r < 4; ++r) {
            float mx = fmaxf(fmaxf(sacc[0][r], sacc[1][r]), fmaxf(sacc[2][r], sacc[3][r]));
#pragma unroll
            for (int off = 1; off < 16; off <<= 1) mx = fmaxf(mx, __shfl_xor(mx, off));
            pm[r] = mx;
            mnew[r] = fmaxf(m_[r], pm[r]);
            sf[r] = __expf(m_[r] - mnew[r]);
            m_[r] = mnew[r];
            ps[r] = 0.f;
        }
#pragma unroll
        for (int ni = 0; ni < 4; ++ni)
#pragma unroll
            for (int r = 0; r < 4; ++r) {
                float p = __expf(sacc[ni][r] - mnew[r]);
                ps[r] += p;
                u16 hh, ll; split1(p, hh, ll);
                Ph_l[w][rgrp * 4 + r][ni * 16 + l16] = hh;
                Pl_l[w][rgrp * 4 + r][ni * 16 + l16] = ll;
            }
#pragma unroll
        for (int r = 0; r < 4; ++r) {
            float s_ = ps[r];
#pragma unroll
            for (int off = 1; off < 16; off <<= 1) s_ += __shfl_xor(s_, off);
            l_[r] = l_[r] * sf[r] + s_;
        }
#pragma unroll
        for (int ni = 0; ni < 4; ++ni)
#pragma unroll
            for (int r = 0; r < 4; ++r) o_[ni][r] *= sf[r];
#pragma unroll
        for (int ks2 = 0; ks2 < 2; ++ks2) {
            bf16x8 pah = *(const bf16x8*)&Ph_l[w][l16][ks2 * 32 + rgrp * 8];
            bf16x8 pal = *(const bf16x8*)&Pl_l[w][l16][ks2 * 32 + rgrp * 8];
            bf16x8 vbh[4], vbl[4];
#pragma unroll
            for (int ni = 0; ni < 4; ++ni) {
                vbh[ni] = *(const bf16x8*)&Vh[ni * 16 + l16][ks2 * 32 + rgrp * 8];
                vbl[ni] = *(const bf16x8*)&Vl[ni * 16 + l16][ks2 * 32 + rgrp * 8];
            }
#pragma unroll
            for (int ni = 0; ni < 4; ++ni) {
                o_[ni] = __builtin_amdgcn_mfma_f32_16x16x32_bf16(pah, vbh[ni], o_[ni], 0, 0, 0);
                o_[ni] = __builtin_amdgcn_mfma_f32_16x16x32_bf16(pah, vbl[ni], o_[ni], 0, 0, 0);
                o_[ni] = __builtin_amdgcn_mfma_f32_16x16x32_bf16(pal, vbh[ni], o_[ni], 0, 0, 0);
            }
        }
        __syncthreads();
    }
#pragma unroll
    for (int r = 0; r < 4; ++r) {
        float inv = 1.f / l_[r];
        int row = q0 + w * 16 + rgrp * 4 + r;
#pragma unroll
        for (int ni = 0; ni < 4; ++ni) {
            float val = o_[ni][r] * inv;
            u16 hh, ll; split1(val, hh, ll);
            size_t o = (size_t)row * MDIM + h * HD + ni * 16 + l16;
            aoh[o] = hh;
            aol[o] = ll;
        }
    }
}

// ---------------- fused RMS norm 2 + router logits + top-8 ----------------
__global__ __launch_bounds__(256) void k_rms2_router(const float* __restrict__ h,
                                                     const float* __restrict__ w,
                                                     const float* __restrict__ gw,
                                                     u16* __restrict__ h2b,
                                                     int* __restrict__ topi,
                                                     float* __restrict__ wts) {
    __shared__ float xr[1024];
    __shared__ float part[4][64];
    __shared__ float red[4];
    int s = blockIdx.x, tid = threadIdx.x;
    const float* row = h + (size_t)s * MDIM;
    float v[4]; float ss = 0.f;
#pragma unroll
    for (int i = 0; i < 4; ++i) { v[i] = row[tid + i * 256]; ss += v[i] * v[i]; }
#pragma unroll
    for (int of = 32; of; of >>= 1) ss += __shfl_xor(ss, of);
    if ((tid & 63) == 0) red[tid >> 6] = ss;
    __syncthreads();
    float tot = red[0] + red[1] + red[2] + red[3];
    float sc = rsqrtf(tot * (1.f / MDIM) + 1e-6f);
#pragma unroll
    for (int i = 0; i < 4; ++i) {
        int c = tid + i * 256;
        float ov = v[i] * sc * w[c];
        xr[c] = ov;
        h2b[(size_t)s * MDIM + c] = f2bf(ov);
    }
    __syncthreads();
    int e = tid & 63, qq = tid >> 6;
    float acc = 0.f;
    for (int i = 0; i < 256; ++i) acc += xr[qq * 256 + i] * gw[(size_t)(qq * 256 + i) * NE + e];
    part[qq][e] = acc;
    __syncthreads();
    if (tid < 64) {
        int lane = tid;
        float lg = part[0][lane] + part[1][lane] + part[2][lane] + part[3][lane];
        float mx = lg;
#pragma unroll
        for (int o = 32; o; o >>= 1) mx = fmaxf(mx, __shfl_xor(mx, o));
        float ex = __expf(lg - mx);
        float sum = ex;
#pragma unroll
        for (int o = 32; o; o >>= 1) sum += __shfl_xor(sum, o);
        float g = ex / sum;
        float cur = g;
        float tv[TOPK]; int ti[TOPK];
        float tsum = 0.f;
#pragma unroll
        for (int k = 0; k < TOPK; ++k) {
            float vv = cur; int ii = lane;
#pragma unroll
            for (int o = 32; o; o >>= 1) {
                float vo = __shfl_xor(vv, o);
                int io = __shfl_xor(ii, o);
                if (vo > vv || (vo == vv && io < ii)) { vv = vo; ii = io; }
            }
            tv[k] = vv; ti[k] = ii; tsum += vv;
            if (lane == ii) cur = -1.f;
        }
        float gs = fmaxf(tsum, 1.1920929e-07f);
        if (lane == 0) {
#pragma unroll
            for (int k = 0; k < TOPK; ++k) {
                topi[s * TOPK + k] = ti[k];
                wts[s * TOPK + k] = tv[k] / gs;
            }
        }
    }
}

// ---------------- parallel rank-major priority / capacity assignment ----------------
__global__ __launch_bounds__(512) void k_slots(const int* __restrict__ topi, int* __restrict__ slots,
                                               int* __restrict__ counts, int* __restrict__ etok) {
    __shared__ int tl[S * TOPK];
    __shared__ int cnt[TOPK][NE];
    __shared__ int base[TOPK][NE];
    int tid = threadIdx.x;
    for (int i = tid; i < S * TOPK; i += 512) tl[i] = topi[i];
    ((int*)cnt)[tid] = 0;
    __syncthreads();
    for (int i = tid; i < S * TOPK; i += 512)
        atomicAdd(&cnt[i & 7][tl[i]], 1);
    __syncthreads();
    if (tid < NE) {
        int acc = 0;
#pragma unroll
        for (int k = 0; k < TOPK; ++k) { base[k][tid] = acc; acc += cnt[k][tid]; }
        counts[tid] = acc < CAP ? acc : CAP;
    }
    __syncthreads();
    int k = tid >> 6, e = tid & 63;
    int rank = base[k][e];
    for (int s = 0; s < S; ++s) {
        if (tl[s * TOPK + k] == e) {
            if (rank < CAP) { slots[s * TOPK + k] = rank; etok[e * CAP + rank] = s; }
            else slots[s * TOPK + k] = -1;
            rank++;
        }
    }
}

// ---------------- final combine: out = h + shared + sum_k w_k * eo[e_k, slot_k] ----------------
__global__ __launch_bounds__(256) void k_combine(const float* __restrict__ h,
                                                 const u16* __restrict__ sh,
                                                 const u16* __restrict__ eo,
                                                 const int* __restrict__ topi,
                                                 const int* __restrict__ slots,
                                                 const float* __restrict__ wts,
                                                 float* __restrict__ out) {
    int s = blockIdx.x, t = threadIdx.x;
    float w[TOPK]; int off[TOPK];
#pragma unroll
    for (int k = 0; k < TOPK; ++k) {
        int sl = slots[s * TOPK + k];
        int ee = topi[s * TOPK + k];
        w[k] = wts[s * TOPK + k];
        off[k] = (sl >= 0) ? ee * CAP + sl : -1;
    }
#pragma unroll
    for (int i = 0; i < 4; ++i) {
        int col = t + i * 256;
        float acc = h[(size_t)s * MDIM + col] + bf2f(sh[(size_t)s * MDIM + col]);
#pragma unroll
        for (int k = 0; k < TOPK; ++k)
            if (off[k] >= 0) acc += w[k] * bf2f(eo[(size_t)off[k] * MDIM + col]);
        out[(size_t)s * MDIM + col] = acc;
    }
}

extern "C" void kernel_launch(void* const* d_in, const int* in_sizes, int n_in,
                              void* d_out, int out_size, void* d_ws, size_t ws_size,
                              hipStream_t stream) {
    (void)in_sizes; (void)n_in; (void)out_size; (void)ws_size;
    const float* hidden = (const float*)d_in[0];
    const float* cosb   = (const float*)d_in[1];
    const float* sinb   = (const float*)d_in[2];
    const float* ln1_w  = (const float*)d_in[3];
    const float* ln2_w  = (const float*)d_in[4];
    const float* qkv_w  = (const float*)d_in[5];
    const float* o_w    = (const float*)d_in[6];
    const float* qn_w   = (const float*)d_in[7];
    const float* kn_w   = (const float*)d_in[8];
    const float* sgu_w  = (const float*)d_in[9];
    const float* sdn_w  = (const float*)d_in[10];
    const float* gate_w = (const float*)d_in[11];
    const float* egu_w  = (const float*)d_in[12];
    const float* edn_w  = (const float*)d_in[13];
    float* out = (float*)d_out;

    char* ws = (char*)d_ws;
    size_t off = 0;
    auto alloc = [&](size_t bytes) -> void* {
        void* p = ws + off;
        off = (off + bytes + 255) & ~(size_t)255;
        return p;
    };
    u16*   hn_hi   = (u16*)  alloc((size_t)S * MDIM * 2);
    u16*   hn_lo   = (u16*)  alloc((size_t)S * MDIM * 2);
    float* qkvb    = (float*)alloc((size_t)S * 2048 * 4);
    u16*   qhb     = (u16*)  alloc((size_t)NH * S * HD * 2);
    u16*   qlb     = (u16*)  alloc((size_t)NH * S * HD * 2);
    u16*   khb     = (u16*)  alloc((size_t)NKV * S * HD * 2);
    u16*   klb     = (u16*)  alloc((size_t)NKV * S * HD * 2);
    u16*   vhb     = (u16*)  alloc((size_t)NKV * S * HD * 2);
    u16*   vlb     = (u16*)  alloc((size_t)NKV * S * HD * 2);
    u16*   ao_hi   = (u16*)  alloc((size_t)S * MDIM * 2);
    u16*   ao_lo   = (u16*)  alloc((size_t)S * MDIM * 2);
    float* hbuf    = (float*)alloc((size_t)S * MDIM * 4);
    u16*   h2b     = (u16*)  alloc((size_t)S * MDIM * 2);
    u16*   gatedS  = (u16*)  alloc((size_t)S * FF * 2);
    u16*   sharedO = (u16*)  alloc((size_t)S * MDIM * 2);
    int*   topi    = (int*)  alloc((size_t)S * TOPK * 4);
    float* wts     = (float*)alloc((size_t)S * TOPK * 4);
    int*   slots   = (int*)  alloc((size_t)S * TOPK * 4);
    int*   counts  = (int*)  alloc((size_t)NE * 4);
    int*   etok    = (int*)  alloc((size_t)NE * CAP * 4);
    u16*   egated  = (u16*)  alloc((size_t)NE * CAP * FF * 2);
    u16*   eo      = (u16*)  alloc((size_t)NE * CAP * MDIM * 2);

    // 1. RMS norm 1 -> hn hi/lo
    k_rms1<<<dim3(S), 256, 0, stream>>>(hidden, ln1_w, hn_hi, hn_lo);
    // 2. QKV projection (3-term split)
    k_gemm_split<0><<<dim3(2048 / 64, S / 64), 256, 0, stream>>>(
        hn_hi, hn_lo, MDIM, qkv_w, 2048, qkvb, 2048, nullptr, S, MDIM);
    // 3. unpack + RoPE + q/k RMS -> pre-split bf16
    k_rope<<<dim3(S * NKV / 4), 256, 0, stream>>>(qkvb, cosb, sinb, qn_w, kn_w,
                                                  qhb, qlb, khb, klb, vhb, vlb);
    // 4. fused flash attention (3-term QK^T and PV, online softmax)
    k_attn<<<dim3(16, NH), 256, 0, stream>>>(qhb, qlb, khb, klb, vhb, vlb, ao_hi, ao_lo);
    // 5. O projection + residual -> h f32 (3-term)
    k_gemm_split<1><<<dim3(MDIM / 64, S / 64), 256, 0, stream>>>(
        ao_hi, ao_lo, MDIM, o_w, MDIM, hbuf, MDIM, hidden, S, MDIM);
    // 6. fused RMS norm 2 + router logits + top-8
    k_rms2_router<<<dim3(S), 256, 0, stream>>>(hbuf, ln2_w, gate_w, h2b, topi, wts);
    // 7. capacity / slot assignment
    k_slots<<<dim3(1), 512, 0, stream>>>(topi, slots, counts, etok);
    // 8. expert-up + shared-up merged (swiglu) -> egated / gatedS (bf16), 3D grid (round-7 form)
    k_gemm_bf<160, 64, true><<<dim3(FF / 64, 2, NE + 4), 256, 0, stream>>>(
        h2b, MDIM, 0, egu_w, (long)MDIM * 2 * FF, 2 * FF,
        egated, FF, (long)CAP * FF, MDIM, FF, counts, etok,
        h2b, sgu_w, gatedS, S);
    // 9. expert-down + shared-down merged -> eo / sharedO (bf16), register-streaming, XCD 1D
    k_gemm_reg<160, 128><<<dim3(1088, 1, 1), 256, 0, stream>>>(
        egated, FF, (long)CAP * FF, edn_w, (long)FF * MDIM, MDIM,
        eo, MDIM, (long)CAP * MDIM, FF, counts,
        gatedS, sdn_w, sharedO, S);
    // 10. combine: out = h + shared + moe
    k_combine<<<dim3(S), 256, 0, stream>>>(hbuf, sharedO, eo, topi, slots, wts, out);
}

// Round 11
// 901.267 us; speedup vs baseline: 1.2731x; 1.2731x over previous
//
#include <hip/hip_runtime.h>

#define S 1024
#define MDIM 1024
#define NH 16
#define HD 64
#define NKV 8
#define FF 3072
#define NE 64
#define TOPK 8
#define CAP 256

typedef unsigned short u16;
typedef __attribute__((ext_vector_type(8))) short bf16x8;
typedef __attribute__((ext_vector_type(4))) float f32x4;

__device__ __forceinline__ u16 f2bf(float f) {
    union { float f; unsigned u; } x; x.f = f;
    unsigned r = x.u + 0x7FFFu + ((x.u >> 16) & 1u);
    return (u16)(r >> 16);
}
__device__ __forceinline__ float bf2f(u16 b) {
    union { unsigned u; float f; } x; x.u = ((unsigned)b) << 16;
    return x.f;
}
__device__ __forceinline__ void split1(float x, u16& h, u16& l) {
    h = f2bf(x);
    l = f2bf(x - bf2f(h));
}
// swizzled column (u16 units) for k-octet G in row `row` of a [R][40] B-tile
__device__ __forceinline__ int swzcol(int row, int G) { return 8 * (G ^ ((row >> 3) & 3)); }

// 16B global->LDS DMA (dest = wave-uniform base + lane*16)
__device__ __forceinline__ void gl_lds16(const u16* g, u16* l) {
    __builtin_amdgcn_global_load_lds(
        (const __attribute__((address_space(1))) unsigned int*)g,
        (__attribute__((address_space(3))) unsigned int*)l, 16, 0, 0);
}

// ---------------- RMS norm 1: writes pre-split bf16 hi/lo ----------------
__global__ __launch_bounds__(256) void k_rms1(const float* __restrict__ x,
                                              const float* __restrict__ w,
                                              u16* __restrict__ ohi,
                                              u16* __restrict__ olo) {
    int s = blockIdx.x;
    const float* row = x + (size_t)s * MDIM;
    float v[4]; float ss = 0.f;
#pragma unroll
    for (int i = 0; i < 4; ++i) { v[i] = row[threadIdx.x + i * 256]; ss += v[i] * v[i]; }
#pragma unroll
    for (int of = 32; of; of >>= 1) ss += __shfl_xor(ss, of);
    __shared__ float red[4];
    int wid = threadIdx.x >> 6;
    if ((threadIdx.x & 63) == 0) red[wid] = ss;
    __syncthreads();
    float tot = red[0] + red[1] + red[2] + red[3];
    float sc = rsqrtf(tot * (1.f / MDIM) + 1e-6f);
#pragma unroll
    for (int i = 0; i < 4; ++i) {
        int c = threadIdx.x + i * 256;
        float ov = v[i] * sc * w[c];
        u16 hh, ll; split1(ov, hh, ll);
        ohi[(size_t)s * MDIM + c] = hh;
        olo[(size_t)s * MDIM + c] = ll;
    }
}

// ---------------- 3-term split GEMM, pipelined + gload_lds A ----------------
// EPI: 0 = f32 out, 1 = f32 out + resid
template <int EPI>
__global__ __launch_bounds__(256) void k_gemm_split(
    const u16* __restrict__ Ahi, const u16* __restrict__ Alo, int lda,
    const float* __restrict__ B, int ldb,
    float* __restrict__ C, int ldc,
    const float* __restrict__ resid, int M, int K) {
    int m0 = blockIdx.y * 64;
    int n0 = blockIdx.x * 64;
    __shared__ u16 Ah[2][64][32];
    __shared__ u16 Al[2][64][32];
    __shared__ u16 Bh[2][64][40];
    __shared__ u16 Bl[2][64][40];
    int tid = threadIdx.x, lane = tid & 63, wid = tid >> 6;
    int wm = (wid >> 1) * 32, wn = (wid & 1) * 32;
    f32x4 acc[2][2] = {};

    int rt = wid * 16 + (lane >> 2);
    int gsrc = (lane & 3) ^ ((lane >> 4) & 3);
    const u16* ahb = Ahi + (size_t)(m0 + rt) * lda + gsrc * 8;
    const u16* alb = Alo + (size_t)(m0 + rt) * lda + gsrc * 8;

    int nB = tid & 63, kbB = tid >> 6;
    int colB = swzcol(nB, kbB);
    float rb[8];
    auto loadB = [&](int k0) {
        const float* bp = B + (size_t)(k0 + kbB * 8) * ldb + n0 + nB;
#pragma unroll
        for (int i = 0; i < 8; ++i) rb[i] = bp[(size_t)i * ldb];
    };
    auto stageA = [&](int b, int k0) {
        gl_lds16(ahb + k0, &Ah[b][wid * 16][0]);
        gl_lds16(alb + k0, &Al[b][wid * 16][0]);
    };
    auto writeB = [&](int b) {
        bf16x8 hh, ll;
#pragma unroll
        for (int i = 0; i < 8; ++i) { u16 h, l; split1(rb[i], h, l); hh[i] = (short)h; ll[i] = (short)l; }
        *(bf16x8*)&Bh[b][nB][colB] = hh;
        *(bf16x8*)&Bl[b][nB][colB] = ll;
    };

    loadB(0); stageA(0, 0); writeB(0);
    __syncthreads();
    int NT = K / 32;
    for (int t = 0; t < NT; ++t) {
        int c = t & 1;
        if (t + 1 < NT) { loadB((t + 1) * 32); stageA(1 - c, (t + 1) * 32); }
        bf16x8 ah[2], al[2], bh[2], bl[2];
#pragma unroll
        for (int mi = 0; mi < 2; ++mi) {
            int r = wm + mi * 16 + (lane & 15);
            int cA = 8 * ((lane >> 4) ^ ((r >> 2) & 3));
            ah[mi] = *(const bf16x8*)&Ah[c][r][cA];
            al[mi] = *(const bf16x8*)&Al[c][r][cA];
        }
#pragma unroll
        for (int ni = 0; ni < 2; ++ni) {
            int r = wn + ni * 16 + (lane & 15);
            int cc = swzcol(r, lane >> 4);
            bh[ni] = *(const bf16x8*)&Bh[c][r][cc];
            bl[ni] = *(const bf16x8*)&Bl[c][r][cc];
        }
#pragma unroll
        for (int mi = 0; mi < 2; ++mi)
#pragma unroll
            for (int ni = 0; ni < 2; ++ni) {
                acc[mi][ni] = __builtin_amdgcn_mfma_f32_16x16x32_bf16(ah[mi], bh[ni], acc[mi][ni], 0, 0, 0);
                acc[mi][ni] = __builtin_amdgcn_mfma_f32_16x16x32_bf16(ah[mi], bl[ni], acc[mi][ni], 0, 0, 0);
                acc[mi][ni] = __builtin_amdgcn_mfma_f32_16x16x32_bf16(al[mi], bh[ni], acc[mi][ni], 0, 0, 0);
            }
        if (t + 1 < NT) { writeB(1 - c); __syncthreads(); }
    }
#pragma unroll
    for (int mi = 0; mi < 2; ++mi)
#pragma unroll
        for (int ni = 0; ni < 2; ++ni)
#pragma unroll
            for (int r = 0; r < 4; ++r) {
                int row = m0 + wm + mi * 16 + (lane >> 4) * 4 + r;
                int col = n0 + wn + ni * 16 + (lane & 15);
                float v = acc[mi][ni][r];
                if constexpr (EPI == 1) v += resid[(size_t)row * ldc + col];
                C[(size_t)row * ldc + col] = v;
            }
}

// ---------------- 1-term bf16 GEMM, 2-phase pipelined; merged expert+shared ----------------
// XCD1D: 1D grid with XCD-affinity mapping (expert e's n-tiles share id%8 -> same XCD L2)
template <int TM, int TN, bool SWIGLU, bool XCD1D>
__global__ __launch_bounds__(256) void k_gemm_bf(
    const u16* __restrict__ A, int lda, long sAe,
    const float* __restrict__ B, long sBe, int ldb,
    u16* __restrict__ C, int ldc, long sCe,
    int K, int pairOff,
    const int* __restrict__ counts, const int* __restrict__ rowidx,
    const u16* __restrict__ Ash, const float* __restrict__ Bsh,
    u16* __restrict__ Csh, int Msh) {
    int z, byy, bxx;
    if constexpr (XCD1D) {
        int id = blockIdx.x;
        if (id < 1024) { byy = id >> 9; int t = id & 511; z = ((t >> 6) << 3) | (t & 7); bxx = (t >> 3) & 7; }
        else { int ms = id - 1024; z = NE + (ms >> 4); byy = (ms >> 3) & 1; bxx = ms & 7; }
    } else {
        z = blockIdx.z; byy = blockIdx.y; bxx = blockIdx.x;
    }
    int tid = threadIdx.x, lane = tid & 63, wid = tid >> 6;
    int M, m0;
    const int* ridx = nullptr;
    if (z >= NE) {
        int mslot = (z - NE) * 2 + byy;
        m0 = mslot * TM;
        M = Msh;
        A = Ash; B = Bsh; C = Csh;
        if (m0 >= M) return;
    } else {
        M = counts[z];
        m0 = byy * TM;
        if (m0 >= M) return;
        A += (size_t)z * sAe;
        B += (size_t)z * sBe;
        C += (size_t)z * sCe;
        if (rowidx) ridx = rowidx + z * CAP;
    }
    int n0 = bxx * TN;

    __shared__ u16 As[2][TM][32];
    __shared__ u16 Bs[2][TN][40];
    __shared__ u16 B2s[2][SWIGLU ? TN : 1][40];

    constexpr int MF = TM / 32;
    constexpr int NI = TN / 32;
    int wm = (wid >> 1) * (TM / 2), wn = (wid & 1) * (TN / 2);

    f32x4 acc[MF][NI] = {};
    f32x4 acc2[SWIGLU ? MF : 1][NI] = {};

    constexpr int NCH = TM / 16;
    constexpr int CPW = (NCH + 3) / 4;
    int arow_in = lane >> 2;
    int gsrc = (lane & 3) ^ ((lane >> 4) & 3);
    const u16* abase[CPW];
#pragma unroll
    for (int i = 0; i < CPW; ++i) {
        int ch = wid + i * 4;
        const u16* p = A;
        if (ch < NCH) {
            int rti = ch * 16 + arow_in;
            int gm = m0 + rti;
            long grow = (gm < M) ? (ridx ? (long)ridx[gm] : (long)gm) : 0;
            p = A + grow * (size_t)lda + gsrc * 8;
        }
        abase[i] = p;
    }
    auto stageA = [&](int b, int k0) {
#pragma unroll
        for (int i = 0; i < CPW; ++i) {
            int ch = wid + i * 4;
            if (ch < NCH) gl_lds16(abase[i] + k0, &As[b][ch * 16][0]);
        }
    };

    constexpr int NKG = 256 / TN;
    constexpr int OPT = 4 / NKG;
    int nB = tid % TN, kgB = tid / TN;
    float rb[OPT][8], rg[SWIGLU ? OPT : 1][8];
    auto loadB = [&](int k0) {
        const float* bp = B + (size_t)(k0 + kgB * OPT * 8) * ldb + n0 + nB;
#pragma unroll
        for (int j = 0; j < OPT; ++j)
#pragma unroll
            for (int i = 0; i < 8; ++i) {
                rb[j][i] = bp[(size_t)(j * 8 + i) * ldb];
                if constexpr (SWIGLU) rg[j][i] = bp[(size_t)(j * 8 + i) * ldb + pairOff];
            }
    };
    auto writeB = [&](int b) {
#pragma unroll
        for (int j = 0; j < OPT; ++j) {
            int col = swzcol(nB, kgB * OPT + j);
            bf16x8 v;
#pragma unroll
            for (int i = 0; i < 8; ++i) v[i] = (short)f2bf(rb[j][i]);
            *(bf16x8*)&Bs[b][nB][col] = v;
            if constexpr (SWIGLU) {
                bf16x8 g;
#pragma unroll
                for (int i = 0; i < 8; ++i) g[i] = (short)f2bf(rg[j][i]);
                *(bf16x8*)&B2s[b][nB][col] = g;
            }
        }
    };

    loadB(0); stageA(0, 0); writeB(0);
    __syncthreads();
    int NT = K / 32;
    for (int t = 0; t < NT; ++t) {
        int c = t & 1;
        if (t + 1 < NT) { loadB((t + 1) * 32); stageA(1 - c, (t + 1) * 32); }
        bf16x8 af[MF], bfr[NI], gfr[SWIGLU ? NI : 1];
#pragma unroll
        for (int mi = 0; mi < MF; ++mi) {
            int r = wm + mi * 16 + (lane & 15);
            int cA = 8 * ((lane >> 4) ^ ((r >> 2) & 3));
            af[mi] = *(const bf16x8*)&As[c][r][cA];
        }
#pragma unroll
        for (int ni = 0; ni < NI; ++ni) {
            int r = wn + ni * 16 + (lane & 15);
            int cB = swzcol(r, lane >> 4);
            bfr[ni] = *(const bf16x8*)&Bs[c][r][cB];
            if constexpr (SWIGLU) gfr[ni] = *(const bf16x8*)&B2s[c][r][cB];
        }
#pragma unroll
        for (int mi = 0; mi < MF; ++mi)
#pragma unroll
            for (int ni = 0; ni < NI; ++ni) {
                acc[mi][ni] = __builtin_amdgcn_mfma_f32_16x16x32_bf16(af[mi], bfr[ni], acc[mi][ni], 0, 0, 0);
                if constexpr (SWIGLU)
                    acc2[mi][ni] = __builtin_amdgcn_mfma_f32_16x16x32_bf16(af[mi], gfr[ni], acc2[mi][ni], 0, 0, 0);
            }
        if (t + 1 < NT) { writeB(1 - c); __syncthreads(); }
    }
#pragma unroll
    for (int mi = 0; mi < MF; ++mi)
#pragma unroll
        for (int ni = 0; ni < NI; ++ni)
#pragma unroll
            for (int r = 0; r < 4; ++r) {
                int row = m0 + wm + mi * 16 + (lane >> 4) * 4 + r;
                int col = n0 + wn + ni * 16 + (lane & 15);
                if (row >= M) continue;
                float x1 = acc[mi][ni][r];
                if constexpr (SWIGLU) {
                    float x2 = acc2[mi][ni][r];
                    x1 = x1 * (x2 / (1.f + __expf(-x2)));
                }
                C[(size_t)row * ldc + col] = f2bf(x1);
            }
}

// ---------------- unpack QKV + RoPE + q/k RMS norm -> pre-split bf16 hi/lo ----------------
__global__ __launch_bounds__(256) void k_rope(const float* __restrict__ qkv,
                                              const float* __restrict__ cosb,
                                              const float* __restrict__ sinb,
                                              const float* __restrict__ qn_w,
                                              const float* __restrict__ kn_w,
                                              u16* __restrict__ qh, u16* __restrict__ ql,
                                              u16* __restrict__ kh, u16* __restrict__ kl,
                                              u16* __restrict__ vh, u16* __restrict__ vl) {
    int wid = threadIdx.x >> 6, lane = threadIdx.x & 63;
    int idx = blockIdx.x * 4 + wid;   // 0..8191
    int s = idx >> 3, j = idx & 7;
    const float* base = qkv + (size_t)s * 2048 + j * 256;
    float c = cosb[s * HD + lane], sn = sinb[s * HD + lane];
    u16 hh, ll;
    split1(base[192 + lane], hh, ll);
    vh[((size_t)j * S + s) * HD + lane] = hh;
    vl[((size_t)j * S + s) * HD + lane] = ll;
#pragma unroll
    for (int r = 0; r < 3; ++r) {
        float x = base[r * 64 + lane];
        float xp = __shfl_xor(x, 32);
        float rot = (lane < 32) ? -xp : xp;
        float y = x * c + rot * sn;
        float ss = y * y;
#pragma unroll
        for (int o = 32; o; o >>= 1) ss += __shfl_xor(ss, o);
        float scale = rsqrtf(ss * (1.f / 64.f) + 1e-6f);
        float outv = y * scale * ((r == 2) ? kn_w[lane] : qn_w[lane]);
        split1(outv, hh, ll);
        if (r == 2) {
            kh[((size_t)j * S + s) * HD + lane] = hh;
            kl[((size_t)j * S + s) * HD + lane] = ll;
        } else {
            qh[((size_t)(j * 2 + r) * S + s) * HD + lane] = hh;
            ql[((size_t)(j * 2 + r) * S + s) * HD + lane] = ll;
        }
    }
}

// ---------------- fused flash attention: per (h, 64-q tile), online softmax ----------------
__global__ __launch_bounds__(256) void k_attn(const u16* __restrict__ qh, const u16* __restrict__ ql,
                                              const u16* __restrict__ kmh, const u16* __restrict__ kml,
                                              const u16* __restrict__ vmh, const u16* __restrict__ vml,
                                              u16* __restrict__ aoh, u16* __restrict__ aol) {
    int qt = 15 - blockIdx.x;       // big tiles first
    int h = blockIdx.y;
    int q0 = qt * 64;
    size_t qoff = (size_t)h * S * HD;
    size_t koff = (size_t)(h >> 1) * S * HD;
    size_t voff = koff;

    __shared__ u16 Vh[64][72];
    __shared__ u16 Vl[64][72];
    __shared__ u16 Ph_l[4][16][72];
    __shared__ u16 Pl_l[4][16][72];

    int tid = threadIdx.x, lane = tid & 63, w = tid >> 6;
    int rgrp = lane >> 4;           // 0..3
    int l16 = lane & 15;

    bf16x8 qfh[2], qfl[2];
#pragma unroll
    for (int ks = 0; ks < 2; ++ks) {
        size_t o = qoff + (size_t)(q0 + w * 16 + l16) * HD + ks * 32 + rgrp * 8;
        qfh[ks] = *(const bf16x8*)(qh + o);
        qfl[ks] = *(const bf16x8*)(ql + o);
    }

    float m_[4], l_[4];
    f32x4 o_[4] = {};
#pragma unroll
    for (int r = 0; r < 4; ++r) { m_[r] = -1e30f; l_[r] = 0.f; }

    for (int kt = 0; kt <= qt; ++kt) {
        int kc = kt * 64;
#pragma unroll
        for (int i = 0; i < 16; ++i) {
            int idx = tid + i * 256;
            int kr = idx >> 6, d = idx & 63;
            Vh[d][kr] = vmh[voff + (size_t)(kc + kr) * HD + d];
            Vl[d][kr] = vml[voff + (size_t)(kc + kr) * HD + d];
        }
        __syncthreads();

        f32x4 sacc[4] = {};
#pragma unroll
        for (int ks = 0; ks < 2; ++ks) {
            bf16x8 bh[4], bl[4];
#pragma unroll
            for (int ni = 0; ni < 4; ++ni) {
                size_t o = koff + (size_t)(kc + ni * 16 + l16) * HD + ks * 32 + rgrp * 8;
                bh[ni] = *(const bf16x8*)(kmh + o);
                bl[ni] = *(const bf16x8*)(kml + o);
            }
#pragma unroll
            for (int ni = 0; ni < 4; ++ni) {
                sacc[ni] = __builtin_amdgcn_mfma_f32_16x16x32_bf16(qfh[ks], bh[ni], sacc[ni], 0, 0, 0);
                sacc[ni] = __builtin_amdgcn_mfma_f32_16x16x32_bf16(qfh[ks], bl[ni], sacc[ni], 0, 0, 0);
                sacc[ni] = __builtin_amdgcn_mfma_f32_16x16x32_bf16(qfl[ks], bh[ni], sacc[ni], 0, 0, 0);
            }
        }
#pragma unroll
        for (int ni = 0; ni < 4; ++ni)
#pragma unroll
            for (int r = 0; r < 4; ++r) {
                int qrow = q0 + w * 16 + rgrp * 4 + r;
                int col = kc + ni * 16 + l16;
                float sv = sacc[ni][r] * 0.125f;
                sacc[ni][r] = (col > qrow) ? -1e30f : sv;
            }
        float pm[4], mnew[4], sf[4], ps[4];
#pragma unroll
        for (int r = 0; r < 4; ++r) {
            float mx = fmaxf(fmaxf(sacc[0][r], sacc[1][r]), fmaxf(sacc[2][r], sacc[3][r]));
#pragma unroll
            for (int off = 1; off < 16; off <<= 1) mx = fmaxf(mx, __shfl_xor(mx, off));
            pm[r] = mx;
            mnew[r] = fmaxf(m_[r], pm[r]);
            sf[r] = __expf(m_[r] - mnew[r]);
            m_[r] = mnew[r];
            ps[r] = 0.f;
        }
#pragma unroll
        for (int ni = 0; ni < 4; ++ni)
#pragma unroll
            for (int r = 0; r < 4; ++r) {
                float p = __expf(sacc[ni][r] - mnew[r]);
                ps[r] += p;
                u16 hh, ll; split1(p, hh, ll);
                Ph_l[w][rgrp * 4 + r][ni * 16 + l16] = hh;
                Pl_l[w][rgrp * 4 + r][ni * 16 + l16] = ll;
            }
#pragma unroll
        for (int r = 0; r < 4; ++r) {
            float s_ = ps[r];
#pragma unroll
            for (int off = 1; off < 16; off <<= 1) s_ += __shfl_xor(s_, off);
            l_[r] = l_[r] * sf[r] + s_;
        }
#pragma unroll
        for (int ni = 0; ni < 4; ++ni)
#pragma unroll
            for (int r = 0; r < 4; ++r) o_[ni][r] *= sf[r];
#pragma unroll
        for (int ks2 = 0; ks2 < 2; ++ks2) {
            bf16x8 pah = *(const bf16x8*)&Ph_l[w][l16][ks2 * 32 + rgrp * 8];
            bf16x8 pal = *(const bf16x8*)&Pl_l[w][l16][ks2 * 32 + rgrp * 8];
            bf16x8 vbh[4], vbl[4];
#pragma unroll
            for (int ni = 0; ni < 4; ++ni) {
                vbh[ni] = *(const bf16x8*)&Vh[ni * 16 + l16][ks2 * 32 + rgrp * 8];
                vbl[ni] = *(const bf16x8*)&Vl[ni * 16 + l16][ks2 * 32 + rgrp * 8];
            }
#pragma unroll
            for (int ni = 0; ni < 4; ++ni) {
                o_[ni] = __builtin_amdgcn_mfma_f32_16x16x32_bf16(pah, vbh[ni], o_[ni], 0, 0, 0);
                o_[ni] = __builtin_amdgcn_mfma_f32_16x16x32_bf16(pah, vbl[ni], o_[ni], 0, 0, 0);
                o_[ni] = __builtin_amdgcn_mfma_f32_16x16x32_bf16(pal, vbh[ni], o_[ni], 0, 0, 0);
            }
        }
        __syncthreads();
    }
#pragma unroll
    for (int r = 0; r < 4; ++r) {
        float inv = 1.f / l_[r];
        int row = q0 + w * 16 + rgrp * 4 + r;
#pragma unroll
        for (int ni = 0; ni < 4; ++ni) {
            float val = o_[ni][r] * inv;
            u16 hh, ll; split1(val, hh, ll);
            size_t o = (size_t)row * MDIM + h * HD + ni * 16 + l16;
            aoh[o] = hh;
            aol[o] = ll;
        }
    }
}

// ---------------- fused RMS norm 2 + router logits + top-8 ----------------
__global__ __launch_bounds__(256) void k_rms2_router(const float* __restrict__ h,
                                                     const float* __restrict__ w,
                                                     const float* __restrict__ gw,
                                                     u16* __restrict__ h2b,
                                                     int* __restrict__ topi,
                                                     float* __restrict__ wts) {
    __shared__ float xr[1024];
    __shared__ float part[4][64];
    __shared__ float red[4];
    int s = blockIdx.x, tid = threadIdx.x;
    const float* row = h + (size_t)s * MDIM;
    float v[4]; float ss = 0.f;
#pragma unroll
    for (int i = 0; i < 4; ++i) { v[i] = row[tid + i * 256]; ss += v[i] * v[i]; }
#pragma unroll
    for (int of = 32; of; of >>= 1) ss += __shfl_xor(ss, of);
    if ((tid & 63) == 0) red[tid >> 6] = ss;
    __syncthreads();
    float tot = red[0] + red[1] + red[2] + red[3];
    float sc = rsqrtf(tot * (1.f / MDIM) + 1e-6f);
#pragma unroll
    for (int i = 0; i < 4; ++i) {
        int c = tid + i * 256;
        float ov = v[i] * sc * w[c];
        xr[c] = ov;
        h2b[(size_t)s * MDIM + c] = f2bf(ov);
    }
    __syncthreads();
    int e = tid & 63, qq = tid >> 6;
    float acc = 0.f;
    for (int i = 0; i < 256; ++i) acc += xr[qq * 256 + i] * gw[(size_t)(qq * 256 + i) * NE + e];
    part[qq][e] = acc;
    __syncthreads();
    if (tid < 64) {
        int lane = tid;
        float lg = part[0][lane] + part[1][lane] + part[2][lane] + part[3][lane];
        float mx = lg;
#pragma unroll
        for (int o = 32; o; o >>= 1) mx = fmaxf(mx, __shfl_xor(mx, o));
        float ex = __expf(lg - mx);
        float sum = ex;
#pragma unroll
        for (int o = 32; o; o >>= 1) sum += __shfl_xor(sum, o);
        float g = ex / sum;
        float cur = g;
        float tv[TOPK]; int ti[TOPK];
        float tsum = 0.f;
#pragma unroll
        for (int k = 0; k < TOPK; ++k) {
            float vv = cur; int ii = lane;
#pragma unroll
            for (int o = 32; o; o >>= 1) {
                float vo = __shfl_xor(vv, o);
                int io = __shfl_xor(ii, o);
                if (vo > vv || (vo == vv && io < ii)) { vv = vo; ii = io; }
            }
            tv[k] = vv; ti[k] = ii; tsum += vv;
            if (lane == ii) cur = -1.f;
        }
        float gs = fmaxf(tsum, 1.1920929e-07f);
        if (lane == 0) {
#pragma unroll
            for (int k = 0; k < TOPK; ++k) {
                topi[s * TOPK + k] = ti[k];
                wts[s * TOPK + k] = tv[k] / gs;
            }
        }
    }
}

// ---------------- parallel rank-major priority / capacity assignment ----------------
__global__ __launch_bounds__(512) void k_slots(const int* __restrict__ topi, int* __restrict__ slots,
                                               int* __restrict__ counts, int* __restrict__ etok) {
    __shared__ int tl[S * TOPK];
    __shared__ int cnt[TOPK][NE];
    __shared__ int base[TOPK][NE];
    int tid = threadIdx.x;
    for (int i = tid; i < S * TOPK; i += 512) tl[i] = topi[i];
    ((int*)cnt)[tid] = 0;
    __syncthreads();
    for (int i = tid; i < S * TOPK; i += 512)
        atomicAdd(&cnt[i & 7][tl[i]], 1);
    __syncthreads();
    if (tid < NE) {
        int acc = 0;
#pragma unroll
        for (int k = 0; k < TOPK; ++k) { base[k][tid] = acc; acc += cnt[k][tid]; }
        counts[tid] = acc < CAP ? acc : CAP;
    }
    __syncthreads();
    int k = tid >> 6, e = tid & 63;
    int rank = base[k][e];
    for (int s = 0; s < S; ++s) {
        if (tl[s * TOPK + k] == e) {
            if (rank < CAP) { slots[s * TOPK + k] = rank; etok[e * CAP + rank] = s; }
            else slots[s * TOPK + k] = -1;
            rank++;
        }
    }
}

// ---------------- final combine: out = h + shared + sum_k w_k * eo[e_k, slot_k] ----------------
__global__ __launch_bounds__(256) void k_combine(const float* __restrict__ h,
                                                 const u16* __restrict__ sh,
                                                 const u16* __restrict__ eo,
                                                 const int* __restrict__ topi,
                                                 const int* __restrict__ slots,
                                                 const float* __restrict__ wts,
                                                 float* __restrict__ out) {
    int s = blockIdx.x, t = threadIdx.x;
    float w[TOPK]; int off[TOPK];
#pragma unroll
    for (int k = 0; k < TOPK; ++k) {
        int sl = slots[s * TOPK + k];
        int ee = topi[s * TOPK + k];
        w[k] = wts[s * TOPK + k];
        off[k] = (sl >= 0) ? ee * CAP + sl : -1;
    }
#pragma unroll
    for (int i = 0; i < 4; ++i) {
        int col = t + i * 256;
        float acc = h[(size_t)s * MDIM + col] + bf2f(sh[(size_t)s * MDIM + col]);
#pragma unroll
        for (int k = 0; k < TOPK; ++k)
            if (off[k] >= 0) acc += w[k] * bf2f(eo[(size_t)off[k] * MDIM + col]);
        out[(size_t)s * MDIM + col] = acc;
    }
}

extern "C" void kernel_launch(void* const* d_in, const int* in_sizes, int n_in,
                              void* d_out, int out_size, void* d_ws, size_t ws_size,
                              hipStream_t stream) {
    (void)in_sizes; (void)n_in; (void)out_size; (void)ws_size;
    const float* hidden = (const float*)d_in[0];
    const float* cosb   = (const float*)d_in[1];
    const float* sinb   = (const float*)d_in[2];
    const float* ln1_w  = (const float*)d_in[3];
    const float* ln2_w  = (const float*)d_in[4];
    const float* qkv_w  = (const float*)d_in[5];
    const float* o_w    = (const float*)d_in[6];
    const float* qn_w   = (const float*)d_in[7];
    const float* kn_w   = (const float*)d_in[8];
    const float* sgu_w  = (const float*)d_in[9];
    const float* sdn_w  = (const float*)d_in[10];
    const float* gate_w = (const float*)d_in[11];
    const float* egu_w  = (const float*)d_in[12];
    const float* edn_w  = (const float*)d_in[13];
    float* out = (float*)d_out;

    char* ws = (char*)d_ws;
    size_t off = 0;
    auto alloc = [&](size_t bytes) -> void* {
        void* p = ws + off;
        off = (off + bytes + 255) & ~(size_t)255;
        return p;
    };
    u16*   hn_hi   = (u16*)  alloc((size_t)S * MDIM * 2);
    u16*   hn_lo   = (u16*)  alloc((size_t)S * MDIM * 2);
    float* qkvb    = (float*)alloc((size_t)S * 2048 * 4);
    u16*   qhb     = (u16*)  alloc((size_t)NH * S * HD * 2);
    u16*   qlb     = (u16*)  alloc((size_t)NH * S * HD * 2);
    u16*   khb     = (u16*)  alloc((size_t)NKV * S * HD * 2);
    u16*   klb     = (u16*)  alloc((size_t)NKV * S * HD * 2);
    u16*   vhb     = (u16*)  alloc((size_t)NKV * S * HD * 2);
    u16*   vlb     = (u16*)  alloc((size_t)NKV * S * HD * 2);
    u16*   ao_hi   = (u16*)  alloc((size_t)S * MDIM * 2);
    u16*   ao_lo   = (u16*)  alloc((size_t)S * MDIM * 2);
    float* hbuf    = (float*)alloc((size_t)S * MDIM * 4);
    u16*   h2b     = (u16*)  alloc((size_t)S * MDIM * 2);
    u16*   gatedS  = (u16*)  alloc((size_t)S * FF * 2);
    u16*   sharedO = (u16*)  alloc((size_t)S * MDIM * 2);
    int*   topi    = (int*)  alloc((size_t)S * TOPK * 4);
    float* wts     = (float*)alloc((size_t)S * TOPK * 4);
    int*   slots   = (int*)  alloc((size_t)S * TOPK * 4);
    int*   counts  = (int*)  alloc((size_t)NE * 4);
    int*   etok    = (int*)  alloc((size_t)NE * CAP * 4);
    u16*   egated  = (u16*)  alloc((size_t)NE * CAP * FF * 2);
    u16*   eo      = (u16*)  alloc((size_t)NE * CAP * MDIM * 2);

    // 1. RMS norm 1 -> hn hi/lo
    k_rms1<<<dim3(S), 256, 0, stream>>>(hidden, ln1_w, hn_hi, hn_lo);
    // 2. QKV projection (3-term split)
    k_gemm_split<0><<<dim3(2048 / 64, S / 64), 256, 0, stream>>>(
        hn_hi, hn_lo, MDIM, qkv_w, 2048, qkvb, 2048, nullptr, S, MDIM);
    // 3. unpack + RoPE + q/k RMS -> pre-split bf16
    k_rope<<<dim3(S * NKV / 4), 256, 0, stream>>>(qkvb, cosb, sinb, qn_w, kn_w,
                                                  qhb, qlb, khb, klb, vhb, vlb);
    // 4. fused flash attention (3-term QK^T and PV, online softmax)
    k_attn<<<dim3(16, NH), 256, 0, stream>>>(qhb, qlb, khb, klb, vhb, vlb, ao_hi, ao_lo);
    // 5. O projection + residual -> h f32 (3-term)
    k_gemm_split<1><<<dim3(MDIM / 64, S / 64), 256, 0, stream>>>(
        ao_hi, ao_lo, MDIM, o_w, MDIM, hbuf, MDIM, hidden, S, MDIM);
    // 6. fused RMS norm 2 + router logits + top-8
    k_rms2_router<<<dim3(S), 256, 0, stream>>>(hbuf, ln2_w, gate_w, h2b, topi, wts);
    // 7. capacity / slot assignment
    k_slots<<<dim3(1), 512, 0, stream>>>(topi, slots, counts, etok);
    // 8. expert-up + shared-up merged (swiglu) -> egated / gatedS (bf16)
    k_gemm_bf<160, 64, true, false><<<dim3(FF / 64, 2, NE + 4), 256, 0, stream>>>(
        h2b, MDIM, 0, egu_w, (long)MDIM * 2 * FF, 2 * FF,
        egated, FF, (long)CAP * FF, MDIM, FF, counts, etok,
        h2b, sgu_w, gatedS, S);
    // 9. expert-down + shared-down merged -> eo / sharedO (bf16), XCD-affinity 1D grid
    k_gemm_bf<160, 128, false, true><<<dim3(1088, 1, 1), 256, 0, stream>>>(
        egated, FF, (long)CAP * FF, edn_w, (long)FF * MDIM, MDIM,
        eo, MDIM, (long)CAP * MDIM, FF, 0, counts, nullptr,
        gatedS, sdn_w, sharedO, S);
    // 10. combine: out = h + shared + moe
    k_combine<<<dim3(S), 256, 0, stream>>>(hbuf, sharedO, eo, topi, slots, wts, out);
}